// Round 2
// baseline (6425.391 us; speedup 1.0000x reference)
//
#include <hip/hip_runtime.h>
#include <math.h>

// Problem dims
#define H_   192
#define W_   192
#define C_   128
#define CS_  24

// branch 0 (m1)
#define DM0  32
#define DI0  64
#define L0   2304
#define LT0  2305
#define NS0  64

// branches 1+2 (m2, shared weights) run as 128 sequences
#define DM2  24
#define DI2  48
#define L12  3072
#define LT12 3073
#define NS12 128

#define DST  16

__device__ __forceinline__ float sigmoidf_(float x){ return 1.f/(1.f+__expf(-x)); }
__device__ __forceinline__ float siluf_(float x){ return x*sigmoidf_(x); }
__device__ __forceinline__ float softplusf_(float x){ return (x > 20.f) ? x : log1pf(__expf(x)); }

// -------- K1: gather + LN + in_proj --------
__global__ __launch_bounds__(256) void k1_b0(const float* __restrict__ x, const float* __restrict__ gt1,
                                             const float* __restrict__ nw, const float* __restrict__ nb,
                                             const float* __restrict__ win, float* __restrict__ XZ,
                                             int seq0, int ntok) {
  __shared__ float wsm[128*32];
  __shared__ float xn[4][DM0];
  for (int i = threadIdx.x; i < 128*32; i += 256) wsm[i] = win[i];
  int wave = threadIdx.x >> 6, lane = threadIdx.x & 63;
  int tok = blockIdx.x*4 + wave;
  bool valid = tok < ntok;
  if (!valid) tok = 0;
  int nl = tok / LT0, t = tok % LT0;
  int n = seq0 + nl;
  float v = 0.f;
  if (lane < DM0) {
    if (t == 0) v = gt1[lane];
    else {
      int s = t - 1; int p = s / 48, q = s % 48;
      int c = lane*4 + (p&1)*2 + (q&1);
      int i = p >> 1, j = q >> 1;
      v = x[c*(H_*W_) + ((n>>3)*CS_ + i)*W_ + (n&7)*CS_ + j];
    }
  }
  float m = v;
  for (int off = 32; off; off >>= 1) m += __shfl_down(m, off);
  m = __shfl(m, 0) * (1.f/DM0);
  float dd = (lane < DM0) ? (v - m) : 0.f;
  float var = dd*dd;
  for (int off = 32; off; off >>= 1) var += __shfl_down(var, off);
  var = __shfl(var, 0) * (1.f/DM0);
  if (lane < DM0) xn[wave][lane] = (v - m) * rsqrtf(var + 1e-5f) * nw[lane] + nb[lane];
  __syncthreads();
  if (!valid) return;
  const float* xw = xn[wave];
  float* outp = XZ + (size_t)tok * (2*DI0);
  for (int o = lane; o < 2*DI0; o += 64) {
    float acc = 0.f; const float* wr = wsm + o*DM0;
    #pragma unroll
    for (int k = 0; k < DM0; k++) acc += xw[k]*wr[k];
    outp[o] = acc;
  }
}

__global__ __launch_bounds__(256) void k1_b12(const float* __restrict__ x, const float* __restrict__ gt2,
                                              const float* __restrict__ nw, const float* __restrict__ nb,
                                              const float* __restrict__ win, float* __restrict__ XZ,
                                              int seq0, int ntok) {
  __shared__ float wsm[96*24];
  __shared__ float xn[4][DM2];
  for (int i = threadIdx.x; i < 96*24; i += 256) wsm[i] = win[i];
  int wave = threadIdx.x >> 6, lane = threadIdx.x & 63;
  int tok = blockIdx.x*4 + wave;
  bool valid = tok < ntok;
  if (!valid) tok = 0;
  int nsl = tok / LT12, t = tok % LT12;
  int gid = seq0 + nsl;
  float v = 0.f;
  if (lane < DM2) {
    if (t == 0) v = gt2[lane];
    else {
      int s = t - 1; int c = s / 24, r = s % 24;
      int n = gid & 63; int br = gid >> 6;        // 0: rows-as-feature, 1: cols-as-feature
      int i = br ? r : lane;
      int j = br ? lane : r;
      v = x[c*(H_*W_) + ((n>>3)*CS_ + i)*W_ + (n&7)*CS_ + j];
    }
  }
  float m = v;
  for (int off = 32; off; off >>= 1) m += __shfl_down(m, off);
  m = __shfl(m, 0) * (1.f/DM2);
  float dd = (lane < DM2) ? (v - m) : 0.f;
  float var = dd*dd;
  for (int off = 32; off; off >>= 1) var += __shfl_down(var, off);
  var = __shfl(var, 0) * (1.f/DM2);
  if (lane < DM2) xn[wave][lane] = (v - m) * rsqrtf(var + 1e-5f) * nw[lane] + nb[lane];
  __syncthreads();
  if (!valid) return;
  const float* xw = xn[wave];
  float* outp = XZ + (size_t)tok * (2*DI2);
  for (int o = lane; o < 2*DI2; o += 64) {
    float acc = 0.f; const float* wr = wsm + o*DM2;
    #pragma unroll
    for (int k = 0; k < DM2; k++) acc += xw[k]*wr[k];
    outp[o] = acc;
  }
}

// -------- K2: conv + silu + x_proj + dt --------
__global__ __launch_bounds__(256) void k2_b0(const float* __restrict__ XZ,
    const float* __restrict__ cw, const float* __restrict__ cb,
    const float* __restrict__ xpw, const float* __restrict__ dtw, const float* __restrict__ dtb,
    float* __restrict__ XS, float* __restrict__ DT, float* __restrict__ BSb, float* __restrict__ CSb,
    int ntok) {
  __shared__ float xs_s[4][DI0];
  __shared__ float dbl_s[4][34];
  int wave = threadIdx.x >> 6, lane = threadIdx.x & 63;
  int tok = blockIdx.x*4 + wave;
  bool valid = tok < ntok;
  if (!valid) tok = 0;
  int t = tok % LT0;
  size_t base = (size_t)(tok - t);
  int d = lane;
  float acc = cb[d];
  #pragma unroll
  for (int k = 0; k < 4; k++) {
    int tt = t - 3 + k;
    if (tt >= 0) acc += XZ[(base + tt)*(2*DI0) + d] * cw[d*4 + k];
  }
  float xsv = siluf_(acc);
  if (valid) XS[(size_t)tok*DI0 + d] = xsv;
  xs_s[wave][d] = xsv;
  __syncthreads();
  if (lane < 34) {
    float a = 0.f; const float* wr = xpw + lane*DI0; const float* xv = xs_s[wave];
    #pragma unroll
    for (int k = 0; k < DI0; k++) a += xv[k]*wr[k];
    dbl_s[wave][lane] = a;
    if (valid) {
      if (lane >= 2 && lane < 18)      BSb[(size_t)tok*DST + (lane-2)]  = a;
      else if (lane >= 18)             CSb[(size_t)tok*DST + (lane-18)] = a;
    }
  }
  __syncthreads();
  float raw = dbl_s[wave][0]*dtw[d*2] + dbl_s[wave][1]*dtw[d*2+1] + dtb[d];
  if (valid) DT[(size_t)tok*DI0 + d] = softplusf_(raw);
}

__global__ __launch_bounds__(256) void k2_b12(const float* __restrict__ XZ,
    const float* __restrict__ cw, const float* __restrict__ cb,
    const float* __restrict__ xpw, const float* __restrict__ dtw, const float* __restrict__ dtb,
    float* __restrict__ XS, float* __restrict__ DT, float* __restrict__ BSb, float* __restrict__ CSb,
    int ntok) {
  __shared__ float xs_s[4][DI2];
  __shared__ float dbl_s[4][34];
  int wave = threadIdx.x >> 6, lane = threadIdx.x & 63;
  int tok = blockIdx.x*4 + wave;
  bool valid = tok < ntok;
  if (!valid) tok = 0;
  int t = tok % LT12;
  size_t base = (size_t)(tok - t);
  if (lane < DI2) {
    int d = lane;
    float acc = cb[d];
    #pragma unroll
    for (int k = 0; k < 4; k++) {
      int tt = t - 3 + k;
      if (tt >= 0) acc += XZ[(base + tt)*(2*DI2) + d] * cw[d*4 + k];
    }
    float xsv = siluf_(acc);
    if (valid) XS[(size_t)tok*DI2 + d] = xsv;
    xs_s[wave][d] = xsv;
  }
  __syncthreads();
  if (lane < 34) {
    float a = 0.f; const float* wr = xpw + lane*DI2; const float* xv = xs_s[wave];
    #pragma unroll
    for (int k = 0; k < DI2; k++) a += xv[k]*wr[k];
    dbl_s[wave][lane] = a;
    if (valid) {
      if (lane >= 2 && lane < 18)      BSb[(size_t)tok*DST + (lane-2)]  = a;
      else if (lane >= 18)             CSb[(size_t)tok*DST + (lane-18)] = a;
    }
  }
  __syncthreads();
  if (lane < DI2 && valid) {
    int d = lane;
    float raw = dbl_s[wave][0]*dtw[d*2] + dbl_s[wave][1]*dtw[d*2+1] + dtb[d];
    DT[(size_t)tok*DI2 + d] = softplusf_(raw);
  }
}

// -------- K3: sequential selective scan (+ skip D, + silu(z) gate), writes gated out over DT --------
__global__ __launch_bounds__(64) void k3_b0(const float* __restrict__ XS, float* __restrict__ DT,
    const float* __restrict__ BSb, const float* __restrict__ CSb, const float* __restrict__ XZ,
    const float* __restrict__ Alog, const float* __restrict__ Dp) {
  int n = blockIdx.x; int d = threadIdx.x;
  float A[DST], h[DST];
  #pragma unroll
  for (int i = 0; i < DST; i++) { A[i] = -__expf(Alog[d*DST + i]); h[i] = 0.f; }
  float Dd = Dp[d];
  size_t base = (size_t)n * LT0;
  for (int t = 0; t < LT0; t++) {
    size_t tb = base + t;
    float dtv = DT[tb*DI0 + d];
    float xsv = XS[tb*DI0 + d];
    float du = dtv * xsv;
    const float4* Bp = (const float4*)(BSb + tb*DST);
    const float4* Cp = (const float4*)(CSb + tb*DST);
    float Bv[DST], Cv[DST];
    ((float4*)Bv)[0]=Bp[0]; ((float4*)Bv)[1]=Bp[1]; ((float4*)Bv)[2]=Bp[2]; ((float4*)Bv)[3]=Bp[3];
    ((float4*)Cv)[0]=Cp[0]; ((float4*)Cv)[1]=Cp[1]; ((float4*)Cv)[2]=Cp[2]; ((float4*)Cv)[3]=Cp[3];
    float y = 0.f;
    #pragma unroll
    for (int i = 0; i < DST; i++) {
      h[i] = h[i]*__expf(dtv*A[i]) + du*Bv[i];
      y += h[i]*Cv[i];
    }
    float z = XZ[tb*(2*DI0) + DI0 + d];
    DT[tb*DI0 + d] = (y + xsv*Dd) * siluf_(z);
  }
}

__global__ __launch_bounds__(64) void k3_b12(const float* __restrict__ XS, float* __restrict__ DT,
    const float* __restrict__ BSb, const float* __restrict__ CSb, const float* __restrict__ XZ,
    const float* __restrict__ Alog, const float* __restrict__ Dp) {
  int n = blockIdx.x; int d = threadIdx.x;   // blockDim = 48
  float A[DST], h[DST];
  #pragma unroll
  for (int i = 0; i < DST; i++) { A[i] = -__expf(Alog[d*DST + i]); h[i] = 0.f; }
  float Dd = Dp[d];
  size_t base = (size_t)n * LT12;
  for (int t = 0; t < LT12; t++) {
    size_t tb = base + t;
    float dtv = DT[tb*DI2 + d];
    float xsv = XS[tb*DI2 + d];
    float du = dtv * xsv;
    const float4* Bp = (const float4*)(BSb + tb*DST);
    const float4* Cp = (const float4*)(CSb + tb*DST);
    float Bv[DST], Cv[DST];
    ((float4*)Bv)[0]=Bp[0]; ((float4*)Bv)[1]=Bp[1]; ((float4*)Bv)[2]=Bp[2]; ((float4*)Bv)[3]=Bp[3];
    ((float4*)Cv)[0]=Cp[0]; ((float4*)Cv)[1]=Cp[1]; ((float4*)Cv)[2]=Cp[2]; ((float4*)Cv)[3]=Cp[3];
    float y = 0.f;
    #pragma unroll
    for (int i = 0; i < DST; i++) {
      h[i] = h[i]*__expf(dtv*A[i]) + du*Bv[i];
      y += h[i]*Cv[i];
    }
    float z = XZ[tb*(2*DI2) + DI2 + d];
    DT[tb*DI2 + d] = (y + xsv*Dd) * siluf_(z);
  }
}

// -------- K4: out_proj + fold scatter. fold: (n,c,i,j) -> h=3n+i/8, w=(i%8)*24+j --------
__global__ __launch_bounds__(256) void k4_b0(const float* __restrict__ G, const float* __restrict__ wo,
                                             float* __restrict__ out, int seq0, int ntokL) {
  __shared__ float wsm[DM0*DI0];
  __shared__ float gs[4][DI0];
  for (int i = threadIdx.x; i < DM0*DI0; i += 256) wsm[i] = wo[i];
  int wave = threadIdx.x >> 6, lane = threadIdx.x & 63;
  int tokL = blockIdx.x*4 + wave;
  bool valid = tokL < ntokL;
  if (!valid) tokL = 0;
  int nl = tokL / L0, s = tokL % L0;
  int n = seq0 + nl;
  size_t tb = (size_t)nl*LT0 + (s + 1);
  gs[wave][lane] = G[tb*DI0 + lane];
  __syncthreads();
  if (valid && lane < DM0) {
    float acc = 0.f; const float* wr = wsm + lane*DI0; const float* gv = gs[wave];
    #pragma unroll
    for (int k = 0; k < DI0; k++) acc += gv[k]*wr[k];
    int p = s / 48, q = s % 48;
    int c = lane*4 + (p&1)*2 + (q&1);
    int i = p >> 1, j = q >> 1;
    int hh = n*3 + (i >> 3);
    int ww = (i & 7)*CS_ + j;
    out[c*(H_*W_) + hh*W_ + ww] = acc * (1.f/3.f);
  }
}

__global__ __launch_bounds__(256) void k4_b12(const float* __restrict__ G, const float* __restrict__ wo,
                                              float* __restrict__ out, int seq0, int ntokL) {
  __shared__ float wsm[DM2*DI2];
  __shared__ float gs[4][DI2];
  for (int i = threadIdx.x; i < DM2*DI2; i += 256) wsm[i] = wo[i];
  int wave = threadIdx.x >> 6, lane = threadIdx.x & 63;
  int tokL = blockIdx.x*4 + wave;
  bool valid = tokL < ntokL;
  if (!valid) tokL = 0;
  int nsl = tokL / L12, s = tokL % L12;
  int gid = seq0 + nsl;
  size_t tb = (size_t)nsl*LT12 + (s + 1);
  if (lane < DI2) gs[wave][lane] = G[tb*DI2 + lane];
  __syncthreads();
  if (valid && lane < DM2) {
    float acc = 0.f; const float* wr = wsm + lane*DI2; const float* gv = gs[wave];
    #pragma unroll
    for (int k = 0; k < DI2; k++) acc += gv[k]*wr[k];
    int c = s / 24, r = s % 24;
    int n = gid & 63; int br = gid >> 6;
    int i = br ? r : lane;
    int j = br ? lane : r;
    int hh = n*3 + (i >> 3);
    int ww = (i & 7)*CS_ + j;
    atomicAdd(&out[c*(H_*W_) + hh*W_ + ww], acc * (1.f/3.f));
  }
}

extern "C" void kernel_launch(void* const* d_in, const int* in_sizes, int n_in,
                              void* d_out, int out_size, void* d_ws, size_t ws_size,
                              hipStream_t stream) {
  const float* x       = (const float*)d_in[0];
  const float* norm_w  = (const float*)d_in[1];
  const float* norm_b  = (const float*)d_in[2];
  const float* norm2_w = (const float*)d_in[3];
  const float* norm2_b = (const float*)d_in[4];
  const float* gt1     = (const float*)d_in[5];
  const float* gt2     = (const float*)d_in[6];
  const float* m1_inw  = (const float*)d_in[7];
  const float* m1_cw   = (const float*)d_in[8];
  const float* m1_cb   = (const float*)d_in[9];
  const float* m1_xpw  = (const float*)d_in[10];
  const float* m1_dtw  = (const float*)d_in[11];
  const float* m1_dtb  = (const float*)d_in[12];
  const float* m1_alog = (const float*)d_in[13];
  const float* m1_D    = (const float*)d_in[14];
  const float* m1_ow   = (const float*)d_in[15];
  const float* m2_inw  = (const float*)d_in[16];
  const float* m2_cw   = (const float*)d_in[17];
  const float* m2_cb   = (const float*)d_in[18];
  const float* m2_xpw  = (const float*)d_in[19];
  const float* m2_dtw  = (const float*)d_in[20];
  const float* m2_dtb  = (const float*)d_in[21];
  const float* m2_alog = (const float*)d_in[22];
  const float* m2_D    = (const float*)d_in[23];
  const float* m2_ow   = (const float*)d_in[24];
  float* out = (float*)d_out;

  size_t wsf = ws_size / sizeof(float);

  // ---- branch 0 (m1), chunked over sequences to fit ws ----
  {
    const size_t per = (size_t)LT0 * (2*DI0 + DI0 + DI0 + 2*DST);  // 663,840 floats/seq
    int cap = (int)(wsf / per); if (cap < 1) cap = 1; if (cap > NS0) cap = NS0;
    float* XZ  = (float*)d_ws;
    float* XS  = XZ + (size_t)cap*LT0*(2*DI0);
    float* DT  = XS + (size_t)cap*LT0*DI0;
    float* BSb = DT + (size_t)cap*LT0*DI0;
    float* CSb = BSb + (size_t)cap*LT0*DST;
    for (int s0 = 0; s0 < NS0; s0 += cap) {
      int cs = (NS0 - s0 < cap) ? (NS0 - s0) : cap;
      int ntok  = cs * LT0;
      int ntokL = cs * L0;
      k1_b0<<<(ntok+3)/4, 256, 0, stream>>>(x, gt1, norm_w, norm_b, m1_inw, XZ, s0, ntok);
      k2_b0<<<(ntok+3)/4, 256, 0, stream>>>(XZ, m1_cw, m1_cb, m1_xpw, m1_dtw, m1_dtb, XS, DT, BSb, CSb, ntok);
      k3_b0<<<cs, 64, 0, stream>>>(XS, DT, BSb, CSb, XZ, m1_alog, m1_D);
      k4_b0<<<(ntokL+3)/4, 256, 0, stream>>>(DT, m1_ow, out, s0, ntokL);
    }
  }

  // ---- branches 1+2 (m2 shared weights; global seq id 0..127, branch = id>>6) ----
  {
    const size_t per = (size_t)LT12 * (2*DI2 + DI2 + DI2 + 2*DST); // 688,352 floats/seq
    int cap = (int)(wsf / per); if (cap < 1) cap = 1; if (cap > NS12) cap = NS12;
    float* XZ  = (float*)d_ws;
    float* XS  = XZ + (size_t)cap*LT12*(2*DI2);
    float* DT  = XS + (size_t)cap*LT12*DI2;
    float* BSb = DT + (size_t)cap*LT12*DI2;
    float* CSb = BSb + (size_t)cap*LT12*DST;
    for (int s0 = 0; s0 < NS12; s0 += cap) {
      int cs = (NS12 - s0 < cap) ? (NS12 - s0) : cap;
      int ntok  = cs * LT12;
      int ntokL = cs * L12;
      k1_b12<<<(ntok+3)/4, 256, 0, stream>>>(x, gt2, norm2_w, norm2_b, m2_inw, XZ, s0, ntok);
      k2_b12<<<(ntok+3)/4, 256, 0, stream>>>(XZ, m2_cw, m2_cb, m2_xpw, m2_dtw, m2_dtb, XS, DT, BSb, CSb, ntok);
      k3_b12<<<cs, 48, 0, stream>>>(XS, DT, BSb, CSb, XZ, m2_alog, m2_D);
      k4_b12<<<(ntokL+3)/4, 256, 0, stream>>>(DT, m2_ow, out, s0, ntokL);
    }
  }
}

// Round 3
// 1880.571 us; speedup vs baseline: 3.4167x; 3.4167x over previous
//
#include <hip/hip_runtime.h>
#include <math.h>

// Problem dims
#define H_   192
#define W_   192
#define C_   128
#define CS_  24

// branch 0 (m1)
#define DM0  32
#define DI0  64
#define L0   2304
#define LT0  2305
#define NS0  64

// branches 1+2 (m2, shared weights) run as 128 sequences
#define DM2  24
#define DI2  48
#define L12  3072
#define LT12 3073
#define NS12 128

#define DST  16
#define NCHUNK 32
#define CL0  ((LT0 + NCHUNK - 1) / NCHUNK)    // 73
#define CL12 ((LT12 + NCHUNK - 1) / NCHUNK)   // 97

__device__ __forceinline__ float sigmoidf_(float x){ return 1.f/(1.f+__expf(-x)); }
__device__ __forceinline__ float siluf_(float x){ return x*sigmoidf_(x); }
__device__ __forceinline__ float softplusf_(float x){ return (x > 20.f) ? x : log1pf(__expf(x)); }

// -------- K1: gather + LN + in_proj --------
__global__ __launch_bounds__(256) void k1_b0(const float* __restrict__ x, const float* __restrict__ gt1,
                                             const float* __restrict__ nw, const float* __restrict__ nb,
                                             const float* __restrict__ win, float* __restrict__ XZ,
                                             int seq0, int ntok) {
  __shared__ float wsm[128*32];
  __shared__ float xn[4][DM0];
  for (int i = threadIdx.x; i < 128*32; i += 256) wsm[i] = win[i];
  int wave = threadIdx.x >> 6, lane = threadIdx.x & 63;
  int tok = blockIdx.x*4 + wave;
  bool valid = tok < ntok;
  if (!valid) tok = 0;
  int nl = tok / LT0, t = tok % LT0;
  int n = seq0 + nl;
  float v = 0.f;
  if (lane < DM0) {
    if (t == 0) v = gt1[lane];
    else {
      int s = t - 1; int p = s / 48, q = s % 48;
      int c = lane*4 + (p&1)*2 + (q&1);
      int i = p >> 1, j = q >> 1;
      v = x[c*(H_*W_) + ((n>>3)*CS_ + i)*W_ + (n&7)*CS_ + j];
    }
  }
  float m = v;
  for (int off = 32; off; off >>= 1) m += __shfl_down(m, off);
  m = __shfl(m, 0) * (1.f/DM0);
  float dd = (lane < DM0) ? (v - m) : 0.f;
  float var = dd*dd;
  for (int off = 32; off; off >>= 1) var += __shfl_down(var, off);
  var = __shfl(var, 0) * (1.f/DM0);
  if (lane < DM0) xn[wave][lane] = (v - m) * rsqrtf(var + 1e-5f) * nw[lane] + nb[lane];
  __syncthreads();
  if (!valid) return;
  const float* xw = xn[wave];
  float* outp = XZ + (size_t)tok * (2*DI0);
  for (int o = lane; o < 2*DI0; o += 64) {
    float acc = 0.f; const float* wr = wsm + o*DM0;
    #pragma unroll
    for (int k = 0; k < DM0; k++) acc += xw[k]*wr[k];
    outp[o] = acc;
  }
}

__global__ __launch_bounds__(256) void k1_b12(const float* __restrict__ x, const float* __restrict__ gt2,
                                              const float* __restrict__ nw, const float* __restrict__ nb,
                                              const float* __restrict__ win, float* __restrict__ XZ,
                                              int seq0, int ntok) {
  __shared__ float wsm[96*24];
  __shared__ float xn[4][DM2];
  for (int i = threadIdx.x; i < 96*24; i += 256) wsm[i] = win[i];
  int wave = threadIdx.x >> 6, lane = threadIdx.x & 63;
  int tok = blockIdx.x*4 + wave;
  bool valid = tok < ntok;
  if (!valid) tok = 0;
  int nsl = tok / LT12, t = tok % LT12;
  int gid = seq0 + nsl;
  float v = 0.f;
  if (lane < DM2) {
    if (t == 0) v = gt2[lane];
    else {
      int s = t - 1; int c = s / 24, r = s % 24;
      int n = gid & 63; int br = gid >> 6;        // 0: rows-as-feature, 1: cols-as-feature
      int i = br ? r : lane;
      int j = br ? lane : r;
      v = x[c*(H_*W_) + ((n>>3)*CS_ + i)*W_ + (n&7)*CS_ + j];
    }
  }
  float m = v;
  for (int off = 32; off; off >>= 1) m += __shfl_down(m, off);
  m = __shfl(m, 0) * (1.f/DM2);
  float dd = (lane < DM2) ? (v - m) : 0.f;
  float var = dd*dd;
  for (int off = 32; off; off >>= 1) var += __shfl_down(var, off);
  var = __shfl(var, 0) * (1.f/DM2);
  if (lane < DM2) xn[wave][lane] = (v - m) * rsqrtf(var + 1e-5f) * nw[lane] + nb[lane];
  __syncthreads();
  if (!valid) return;
  const float* xw = xn[wave];
  float* outp = XZ + (size_t)tok * (2*DI2);
  for (int o = lane; o < 2*DI2; o += 64) {
    float acc = 0.f; const float* wr = wsm + o*DM2;
    #pragma unroll
    for (int k = 0; k < DM2; k++) acc += xw[k]*wr[k];
    outp[o] = acc;
  }
}

// -------- K2: conv + silu + x_proj + dt --------
__global__ __launch_bounds__(256) void k2_b0(const float* __restrict__ XZ,
    const float* __restrict__ cw, const float* __restrict__ cb,
    const float* __restrict__ xpw, const float* __restrict__ dtw, const float* __restrict__ dtb,
    float* __restrict__ XS, float* __restrict__ DT, float* __restrict__ BSb, float* __restrict__ CSb,
    int ntok) {
  __shared__ float xs_s[4][DI0];
  __shared__ float dbl_s[4][34];
  int wave = threadIdx.x >> 6, lane = threadIdx.x & 63;
  int tok = blockIdx.x*4 + wave;
  bool valid = tok < ntok;
  if (!valid) tok = 0;
  int t = tok % LT0;
  size_t base = (size_t)(tok - t);
  int d = lane;
  float acc = cb[d];
  #pragma unroll
  for (int k = 0; k < 4; k++) {
    int tt = t - 3 + k;
    if (tt >= 0) acc += XZ[(base + tt)*(2*DI0) + d] * cw[d*4 + k];
  }
  float xsv = siluf_(acc);
  if (valid) XS[(size_t)tok*DI0 + d] = xsv;
  xs_s[wave][d] = xsv;
  __syncthreads();
  if (lane < 34) {
    float a = 0.f; const float* wr = xpw + lane*DI0; const float* xv = xs_s[wave];
    #pragma unroll
    for (int k = 0; k < DI0; k++) a += xv[k]*wr[k];
    dbl_s[wave][lane] = a;
    if (valid) {
      if (lane >= 2 && lane < 18)      BSb[(size_t)tok*DST + (lane-2)]  = a;
      else if (lane >= 18)             CSb[(size_t)tok*DST + (lane-18)] = a;
    }
  }
  __syncthreads();
  float raw = dbl_s[wave][0]*dtw[d*2] + dbl_s[wave][1]*dtw[d*2+1] + dtb[d];
  if (valid) DT[(size_t)tok*DI0 + d] = softplusf_(raw);
}

__global__ __launch_bounds__(256) void k2_b12(const float* __restrict__ XZ,
    const float* __restrict__ cw, const float* __restrict__ cb,
    const float* __restrict__ xpw, const float* __restrict__ dtw, const float* __restrict__ dtb,
    float* __restrict__ XS, float* __restrict__ DT, float* __restrict__ BSb, float* __restrict__ CSb,
    int ntok) {
  __shared__ float xs_s[4][DI2];
  __shared__ float dbl_s[4][34];
  int wave = threadIdx.x >> 6, lane = threadIdx.x & 63;
  int tok = blockIdx.x*4 + wave;
  bool valid = tok < ntok;
  if (!valid) tok = 0;
  int t = tok % LT12;
  size_t base = (size_t)(tok - t);
  if (lane < DI2) {
    int d = lane;
    float acc = cb[d];
    #pragma unroll
    for (int k = 0; k < 4; k++) {
      int tt = t - 3 + k;
      if (tt >= 0) acc += XZ[(base + tt)*(2*DI2) + d] * cw[d*4 + k];
    }
    float xsv = siluf_(acc);
    if (valid) XS[(size_t)tok*DI2 + d] = xsv;
    xs_s[wave][d] = xsv;
  }
  __syncthreads();
  if (lane < 34) {
    float a = 0.f; const float* wr = xpw + lane*DI2; const float* xv = xs_s[wave];
    #pragma unroll
    for (int k = 0; k < DI2; k++) a += xv[k]*wr[k];
    dbl_s[wave][lane] = a;
    if (valid) {
      if (lane >= 2 && lane < 18)      BSb[(size_t)tok*DST + (lane-2)]  = a;
      else if (lane >= 18)             CSb[(size_t)tok*DST + (lane-18)] = a;
    }
  }
  __syncthreads();
  if (lane < DI2 && valid) {
    int d = lane;
    float raw = dbl_s[wave][0]*dtw[d*2] + dbl_s[wave][1]*dtw[d*2+1] + dtb[d];
    DT[(size_t)tok*DI2 + d] = softplusf_(raw);
  }
}

// -------- K3: chunk-parallel selective scan --------
// Pass 1: per (seq,chunk,d) compose chunk transition: P = prod(a_t), S = sum(suffixprod*b_t)
template<int DI, int LT, int CL>
__global__ void scan1(const float* __restrict__ XS, const float* __restrict__ DT,
                      const float* __restrict__ BSb, const float* __restrict__ Alog,
                      float* __restrict__ PRD, float* __restrict__ ACC) {
  int sc = blockIdx.x / NCHUNK, c = blockIdx.x % NCHUNK;
  int d = threadIdx.x;
  float A[DST], P[DST], S[DST];
  const float4* Ap = (const float4*)(Alog + d*DST);
  #pragma unroll
  for (int q = 0; q < 4; q++) {
    float4 av = Ap[q];
    A[q*4+0] = -__expf(av.x); A[q*4+1] = -__expf(av.y);
    A[q*4+2] = -__expf(av.z); A[q*4+3] = -__expf(av.w);
  }
  #pragma unroll
  for (int i = 0; i < DST; i++) { P[i] = 1.f; S[i] = 0.f; }
  int t0 = c*CL, t1 = t0 + CL; if (t1 > LT) t1 = LT;
  size_t base = (size_t)sc * LT;
  for (int t = t0; t < t1; t++) {
    size_t tb = base + t;
    float dtv = DT[tb*DI + d];
    float xsv = XS[tb*DI + d];
    float du = dtv * xsv;
    const float4* Bp = (const float4*)(BSb + tb*DST);
    float Bv[DST];
    ((float4*)Bv)[0]=Bp[0]; ((float4*)Bv)[1]=Bp[1]; ((float4*)Bv)[2]=Bp[2]; ((float4*)Bv)[3]=Bp[3];
    #pragma unroll
    for (int i = 0; i < DST; i++) {
      float a = __expf(dtv*A[i]);
      P[i] *= a;
      S[i] = S[i]*a + du*Bv[i];
    }
  }
  float* pp = PRD + (((size_t)sc*NCHUNK + c)*DI + d)*DST;
  float* sp = ACC + (((size_t)sc*NCHUNK + c)*DI + d)*DST;
  #pragma unroll
  for (int q = 0; q < 4; q++) {
    ((float4*)pp)[q] = ((float4*)P)[q];
    ((float4*)sp)[q] = ((float4*)S)[q];
  }
}

// Pass 2: chunk-level scan per (seq,d,i); leaves h_init for each chunk in ACC
template<int DI>
__global__ __launch_bounds__(256) void scan2(const float* __restrict__ PRD, float* __restrict__ ACC, int nthread) {
  int tid = blockIdx.x*256 + threadIdx.x;
  if (tid >= nthread) return;
  int sc = tid / (DI*DST);
  int rem = tid % (DI*DST);
  float h = 0.f;
  size_t idx = (size_t)sc*NCHUNK*DI*DST + rem;
  #pragma unroll 4
  for (int c = 0; c < NCHUNK; c++) {
    float p = PRD[idx];
    float s = ACC[idx];
    ACC[idx] = h;
    h = p*h + s;
    idx += (size_t)DI*DST;
  }
}

// Pass 3: re-run recurrence from h_init, emit gated output into DT
template<int DI, int LT, int CL>
__global__ void scan3(const float* __restrict__ XS, float* __restrict__ DT,
                      const float* __restrict__ BSb, const float* __restrict__ CSb,
                      const float* __restrict__ XZ, const float* __restrict__ Alog,
                      const float* __restrict__ Dp, const float* __restrict__ ACC) {
  int sc = blockIdx.x / NCHUNK, c = blockIdx.x % NCHUNK;
  int d = threadIdx.x;
  float A[DST], h[DST];
  const float4* Ap = (const float4*)(Alog + d*DST);
  #pragma unroll
  for (int q = 0; q < 4; q++) {
    float4 av = Ap[q];
    A[q*4+0] = -__expf(av.x); A[q*4+1] = -__expf(av.y);
    A[q*4+2] = -__expf(av.z); A[q*4+3] = -__expf(av.w);
  }
  const float4* hp = (const float4*)(ACC + (((size_t)sc*NCHUNK + c)*DI + d)*DST);
  #pragma unroll
  for (int q = 0; q < 4; q++) ((float4*)h)[q] = hp[q];
  float Dd = Dp[d];
  int t0 = c*CL, t1 = t0 + CL; if (t1 > LT) t1 = LT;
  size_t base = (size_t)sc * LT;
  for (int t = t0; t < t1; t++) {
    size_t tb = base + t;
    float dtv = DT[tb*DI + d];
    float xsv = XS[tb*DI + d];
    float du = dtv * xsv;
    const float4* Bp = (const float4*)(BSb + tb*DST);
    const float4* Cp = (const float4*)(CSb + tb*DST);
    float Bv[DST], Cv[DST];
    ((float4*)Bv)[0]=Bp[0]; ((float4*)Bv)[1]=Bp[1]; ((float4*)Bv)[2]=Bp[2]; ((float4*)Bv)[3]=Bp[3];
    ((float4*)Cv)[0]=Cp[0]; ((float4*)Cv)[1]=Cp[1]; ((float4*)Cv)[2]=Cp[2]; ((float4*)Cv)[3]=Cp[3];
    float y = 0.f;
    #pragma unroll
    for (int i = 0; i < DST; i++) {
      float a = __expf(dtv*A[i]);
      h[i] = h[i]*a + du*Bv[i];
      y += h[i]*Cv[i];
    }
    float z = XZ[tb*(2*DI) + DI + d];
    DT[tb*DI + d] = (y + xsv*Dd) * siluf_(z);
  }
}

// -------- K4: out_proj + fold scatter. fold: (n,c,i,j) -> h=3n+i/8, w=(i%8)*24+j --------
__global__ __launch_bounds__(256) void k4_b0(const float* __restrict__ G, const float* __restrict__ wo,
                                             float* __restrict__ out, int seq0, int ntokL) {
  __shared__ float wsm[DM0*DI0];
  __shared__ float gs[4][DI0];
  for (int i = threadIdx.x; i < DM0*DI0; i += 256) wsm[i] = wo[i];
  int wave = threadIdx.x >> 6, lane = threadIdx.x & 63;
  int tokL = blockIdx.x*4 + wave;
  bool valid = tokL < ntokL;
  if (!valid) tokL = 0;
  int nl = tokL / L0, s = tokL % L0;
  int n = seq0 + nl;
  size_t tb = (size_t)nl*LT0 + (s + 1);
  gs[wave][lane] = G[tb*DI0 + lane];
  __syncthreads();
  if (valid && lane < DM0) {
    float acc = 0.f; const float* wr = wsm + lane*DI0; const float* gv = gs[wave];
    #pragma unroll
    for (int k = 0; k < DI0; k++) acc += gv[k]*wr[k];
    int p = s / 48, q = s % 48;
    int c = lane*4 + (p&1)*2 + (q&1);
    int i = p >> 1, j = q >> 1;
    int hh = n*3 + (i >> 3);
    int ww = (i & 7)*CS_ + j;
    out[c*(H_*W_) + hh*W_ + ww] = acc * (1.f/3.f);
  }
}

__global__ __launch_bounds__(256) void k4_b12(const float* __restrict__ G, const float* __restrict__ wo,
                                              float* __restrict__ out, int seq0, int ntokL) {
  __shared__ float wsm[DM2*DI2];
  __shared__ float gs[4][DI2];
  for (int i = threadIdx.x; i < DM2*DI2; i += 256) wsm[i] = wo[i];
  int wave = threadIdx.x >> 6, lane = threadIdx.x & 63;
  int tokL = blockIdx.x*4 + wave;
  bool valid = tokL < ntokL;
  if (!valid) tokL = 0;
  int nsl = tokL / L12, s = tokL % L12;
  int gid = seq0 + nsl;
  size_t tb = (size_t)nsl*LT12 + (s + 1);
  if (lane < DI2) gs[wave][lane] = G[tb*DI2 + lane];
  __syncthreads();
  if (valid && lane < DM2) {
    float acc = 0.f; const float* wr = wsm + lane*DI2; const float* gv = gs[wave];
    #pragma unroll
    for (int k = 0; k < DI2; k++) acc += gv[k]*wr[k];
    int c = s / 24, r = s % 24;
    int n = gid & 63; int br = gid >> 6;
    int i = br ? r : lane;
    int j = br ? lane : r;
    int hh = n*3 + (i >> 3);
    int ww = (i & 7)*CS_ + j;
    atomicAdd(&out[c*(H_*W_) + hh*W_ + ww], acc * (1.f/3.f));
  }
}

extern "C" void kernel_launch(void* const* d_in, const int* in_sizes, int n_in,
                              void* d_out, int out_size, void* d_ws, size_t ws_size,
                              hipStream_t stream) {
  const float* x       = (const float*)d_in[0];
  const float* norm_w  = (const float*)d_in[1];
  const float* norm_b  = (const float*)d_in[2];
  const float* norm2_w = (const float*)d_in[3];
  const float* norm2_b = (const float*)d_in[4];
  const float* gt1     = (const float*)d_in[5];
  const float* gt2     = (const float*)d_in[6];
  const float* m1_inw  = (const float*)d_in[7];
  const float* m1_cw   = (const float*)d_in[8];
  const float* m1_cb   = (const float*)d_in[9];
  const float* m1_xpw  = (const float*)d_in[10];
  const float* m1_dtw  = (const float*)d_in[11];
  const float* m1_dtb  = (const float*)d_in[12];
  const float* m1_alog = (const float*)d_in[13];
  const float* m1_D    = (const float*)d_in[14];
  const float* m1_ow   = (const float*)d_in[15];
  const float* m2_inw  = (const float*)d_in[16];
  const float* m2_cw   = (const float*)d_in[17];
  const float* m2_cb   = (const float*)d_in[18];
  const float* m2_xpw  = (const float*)d_in[19];
  const float* m2_dtw  = (const float*)d_in[20];
  const float* m2_dtb  = (const float*)d_in[21];
  const float* m2_alog = (const float*)d_in[22];
  const float* m2_D    = (const float*)d_in[23];
  const float* m2_ow   = (const float*)d_in[24];
  float* out = (float*)d_out;

  size_t wsf = ws_size / sizeof(float);

  // ---- branch 0 (m1), chunked over sequences to fit ws ----
  {
    const size_t perState = (size_t)NCHUNK*DI0*DST;                          // 32768
    const size_t per = (size_t)LT0*(2*DI0 + DI0 + DI0 + 2*DST) + 2*perState; // 729,376 floats/seq
    int cap = (int)(wsf / per); if (cap < 1) cap = 1; if (cap > NS0) cap = NS0;
    float* XZ  = (float*)d_ws;
    float* XS  = XZ + (size_t)cap*LT0*(2*DI0);
    float* DT  = XS + (size_t)cap*LT0*DI0;
    float* BSb = DT + (size_t)cap*LT0*DI0;
    float* CSb = BSb + (size_t)cap*LT0*DST;
    float* PRD = CSb + (size_t)cap*LT0*DST;
    float* ACC = PRD + (size_t)cap*perState;
    for (int s0 = 0; s0 < NS0; s0 += cap) {
      int cs = (NS0 - s0 < cap) ? (NS0 - s0) : cap;
      int ntok  = cs * LT0;
      int ntokL = cs * L0;
      k1_b0<<<(ntok+3)/4, 256, 0, stream>>>(x, gt1, norm_w, norm_b, m1_inw, XZ, s0, ntok);
      k2_b0<<<(ntok+3)/4, 256, 0, stream>>>(XZ, m1_cw, m1_cb, m1_xpw, m1_dtw, m1_dtb, XS, DT, BSb, CSb, ntok);
      scan1<DI0, LT0, CL0><<<cs*NCHUNK, DI0, 0, stream>>>(XS, DT, BSb, m1_alog, PRD, ACC);
      scan2<DI0><<<(cs*DI0*DST+255)/256, 256, 0, stream>>>(PRD, ACC, cs*DI0*DST);
      scan3<DI0, LT0, CL0><<<cs*NCHUNK, DI0, 0, stream>>>(XS, DT, BSb, CSb, XZ, m1_alog, m1_D, ACC);
      k4_b0<<<(ntokL+3)/4, 256, 0, stream>>>(DT, m1_ow, out, s0, ntokL);
    }
  }

  // ---- branches 1+2 (m2 shared weights; global seq id 0..127, branch = id>>6) ----
  {
    const size_t perState = (size_t)NCHUNK*DI2*DST;                           // 24576
    const size_t per = (size_t)LT12*(2*DI2 + DI2 + DI2 + 2*DST) + 2*perState; // 737,504 floats/seq
    int cap = (int)(wsf / per); if (cap < 1) cap = 1; if (cap > NS12) cap = NS12;
    float* XZ  = (float*)d_ws;
    float* XS  = XZ + (size_t)cap*LT12*(2*DI2);
    float* DT  = XS + (size_t)cap*LT12*DI2;
    float* BSb = DT + (size_t)cap*LT12*DI2;
    float* CSb = BSb + (size_t)cap*LT12*DST;
    float* PRD = CSb + (size_t)cap*LT12*DST;
    float* ACC = PRD + (size_t)cap*perState;
    for (int s0 = 0; s0 < NS12; s0 += cap) {
      int cs = (NS12 - s0 < cap) ? (NS12 - s0) : cap;
      int ntok  = cs * LT12;
      int ntokL = cs * L12;
      k1_b12<<<(ntok+3)/4, 256, 0, stream>>>(x, gt2, norm2_w, norm2_b, m2_inw, XZ, s0, ntok);
      k2_b12<<<(ntok+3)/4, 256, 0, stream>>>(XZ, m2_cw, m2_cb, m2_xpw, m2_dtw, m2_dtb, XS, DT, BSb, CSb, ntok);
      scan1<DI2, LT12, CL12><<<cs*NCHUNK, DI2, 0, stream>>>(XS, DT, BSb, m2_alog, PRD, ACC);
      scan2<DI2><<<(cs*DI2*DST+255)/256, 256, 0, stream>>>(PRD, ACC, cs*DI2*DST);
      scan3<DI2, LT12, CL12><<<cs*NCHUNK, DI2, 0, stream>>>(XS, DT, BSb, CSb, XZ, m2_alog, m2_D, ACC);
      k4_b12<<<(ntokL+3)/4, 256, 0, stream>>>(DT, m2_ow, out, s0, ntokL);
    }
  }
}

// Round 4
// 1620.115 us; speedup vs baseline: 3.9660x; 1.1608x over previous
//
#include <hip/hip_runtime.h>
#include <math.h>

// Problem dims
#define H_   192
#define W_   192
#define C_   128
#define CS_  24

// branch 0 (m1)
#define DM0  32
#define DI0  64
#define L0   2304
#define LT0  2305
#define NS0  64

// branches 1+2 (m2, shared weights) run as 128 sequences
#define DM2  24
#define DI2  48
#define L12  3072
#define LT12 3073
#define NS12 128

#define DST  16
#define NCHUNK 32
#define CL0  ((LT0 + NCHUNK - 1) / NCHUNK)    // 73
#define CL12 ((LT12 + NCHUNK - 1) / NCHUNK)   // 97

__device__ __forceinline__ float sigmoidf_(float x){ return 1.f/(1.f+__expf(-x)); }
__device__ __forceinline__ float siluf_(float x){ return x*sigmoidf_(x); }
__device__ __forceinline__ float softplusf_(float x){ return (x > 20.f) ? x : log1pf(__expf(x)); }

// -------- K1: gather + LN + in_proj --------
__global__ __launch_bounds__(256) void k1_b0(const float* __restrict__ x, const float* __restrict__ gt1,
                                             const float* __restrict__ nw, const float* __restrict__ nb,
                                             const float* __restrict__ win, float* __restrict__ XZ,
                                             int seq0, int ntok) {
  __shared__ float wsm[128*32];
  __shared__ float xn[4][DM0];
  for (int i = threadIdx.x; i < 128*32; i += 256) wsm[i] = win[i];
  int wave = threadIdx.x >> 6, lane = threadIdx.x & 63;
  int tok = blockIdx.x*4 + wave;
  bool valid = tok < ntok;
  if (!valid) tok = 0;
  int nl = tok / LT0, t = tok % LT0;
  int n = seq0 + nl;
  float v = 0.f;
  if (lane < DM0) {
    if (t == 0) v = gt1[lane];
    else {
      int s = t - 1; int p = s / 48, q = s % 48;
      int c = lane*4 + (p&1)*2 + (q&1);
      int i = p >> 1, j = q >> 1;
      v = x[c*(H_*W_) + ((n>>3)*CS_ + i)*W_ + (n&7)*CS_ + j];
    }
  }
  float m = v;
  for (int off = 32; off; off >>= 1) m += __shfl_down(m, off);
  m = __shfl(m, 0) * (1.f/DM0);
  float dd = (lane < DM0) ? (v - m) : 0.f;
  float var = dd*dd;
  for (int off = 32; off; off >>= 1) var += __shfl_down(var, off);
  var = __shfl(var, 0) * (1.f/DM0);
  if (lane < DM0) xn[wave][lane] = (v - m) * rsqrtf(var + 1e-5f) * nw[lane] + nb[lane];
  __syncthreads();
  if (!valid) return;
  const float* xw = xn[wave];
  float* outp = XZ + (size_t)tok * (2*DI0);
  for (int o = lane; o < 2*DI0; o += 64) {
    float acc = 0.f; const float* wr = wsm + o*DM0;
    #pragma unroll
    for (int k = 0; k < DM0; k++) acc += xw[k]*wr[k];
    outp[o] = acc;
  }
}

__global__ __launch_bounds__(256) void k1_b12(const float* __restrict__ x, const float* __restrict__ gt2,
                                              const float* __restrict__ nw, const float* __restrict__ nb,
                                              const float* __restrict__ win, float* __restrict__ XZ,
                                              int seq0, int ntok) {
  __shared__ float wsm[96*24];
  __shared__ float xn[4][DM2];
  for (int i = threadIdx.x; i < 96*24; i += 256) wsm[i] = win[i];
  int wave = threadIdx.x >> 6, lane = threadIdx.x & 63;
  int tok = blockIdx.x*4 + wave;
  bool valid = tok < ntok;
  if (!valid) tok = 0;
  int nsl = tok / LT12, t = tok % LT12;
  int gid = seq0 + nsl;
  float v = 0.f;
  if (lane < DM2) {
    if (t == 0) v = gt2[lane];
    else {
      int s = t - 1; int c = s / 24, r = s % 24;
      int n = gid & 63; int br = gid >> 6;        // 0: rows-as-feature, 1: cols-as-feature
      int i = br ? r : lane;
      int j = br ? lane : r;
      v = x[c*(H_*W_) + ((n>>3)*CS_ + i)*W_ + (n&7)*CS_ + j];
    }
  }
  float m = v;
  for (int off = 32; off; off >>= 1) m += __shfl_down(m, off);
  m = __shfl(m, 0) * (1.f/DM2);
  float dd = (lane < DM2) ? (v - m) : 0.f;
  float var = dd*dd;
  for (int off = 32; off; off >>= 1) var += __shfl_down(var, off);
  var = __shfl(var, 0) * (1.f/DM2);
  if (lane < DM2) xn[wave][lane] = (v - m) * rsqrtf(var + 1e-5f) * nw[lane] + nb[lane];
  __syncthreads();
  if (!valid) return;
  const float* xw = xn[wave];
  float* outp = XZ + (size_t)tok * (2*DI2);
  for (int o = lane; o < 2*DI2; o += 64) {
    float acc = 0.f; const float* wr = wsm + o*DM2;
    #pragma unroll
    for (int k = 0; k < DM2; k++) acc += xw[k]*wr[k];
    outp[o] = acc;
  }
}

// -------- K2: conv + silu + x_proj + dt --------
__global__ __launch_bounds__(256) void k2_b0(const float* __restrict__ XZ,
    const float* __restrict__ cw, const float* __restrict__ cb,
    const float* __restrict__ xpw, const float* __restrict__ dtw, const float* __restrict__ dtb,
    float* __restrict__ XS, float* __restrict__ DT, float* __restrict__ BSb, float* __restrict__ CSb,
    int ntok) {
  __shared__ float xs_s[4][DI0];
  __shared__ float dbl_s[4][34];
  int wave = threadIdx.x >> 6, lane = threadIdx.x & 63;
  int tok = blockIdx.x*4 + wave;
  bool valid = tok < ntok;
  if (!valid) tok = 0;
  int t = tok % LT0;
  size_t base = (size_t)(tok - t);
  int d = lane;
  float acc = cb[d];
  #pragma unroll
  for (int k = 0; k < 4; k++) {
    int tt = t - 3 + k;
    if (tt >= 0) acc += XZ[(base + tt)*(2*DI0) + d] * cw[d*4 + k];
  }
  float xsv = siluf_(acc);
  if (valid) XS[(size_t)tok*DI0 + d] = xsv;
  xs_s[wave][d] = xsv;
  __syncthreads();
  if (lane < 34) {
    float a = 0.f; const float* wr = xpw + lane*DI0; const float* xv = xs_s[wave];
    #pragma unroll
    for (int k = 0; k < DI0; k++) a += xv[k]*wr[k];
    dbl_s[wave][lane] = a;
    if (valid) {
      if (lane >= 2 && lane < 18)      BSb[(size_t)tok*DST + (lane-2)]  = a;
      else if (lane >= 18)             CSb[(size_t)tok*DST + (lane-18)] = a;
    }
  }
  __syncthreads();
  float raw = dbl_s[wave][0]*dtw[d*2] + dbl_s[wave][1]*dtw[d*2+1] + dtb[d];
  if (valid) DT[(size_t)tok*DI0 + d] = softplusf_(raw);
}

__global__ __launch_bounds__(256) void k2_b12(const float* __restrict__ XZ,
    const float* __restrict__ cw, const float* __restrict__ cb,
    const float* __restrict__ xpw, const float* __restrict__ dtw, const float* __restrict__ dtb,
    float* __restrict__ XS, float* __restrict__ DT, float* __restrict__ BSb, float* __restrict__ CSb,
    int ntok) {
  __shared__ float xs_s[4][DI2];
  __shared__ float dbl_s[4][34];
  int wave = threadIdx.x >> 6, lane = threadIdx.x & 63;
  int tok = blockIdx.x*4 + wave;
  bool valid = tok < ntok;
  if (!valid) tok = 0;
  int t = tok % LT12;
  size_t base = (size_t)(tok - t);
  if (lane < DI2) {
    int d = lane;
    float acc = cb[d];
    #pragma unroll
    for (int k = 0; k < 4; k++) {
      int tt = t - 3 + k;
      if (tt >= 0) acc += XZ[(base + tt)*(2*DI2) + d] * cw[d*4 + k];
    }
    float xsv = siluf_(acc);
    if (valid) XS[(size_t)tok*DI2 + d] = xsv;
    xs_s[wave][d] = xsv;
  }
  __syncthreads();
  if (lane < 34) {
    float a = 0.f; const float* wr = xpw + lane*DI2; const float* xv = xs_s[wave];
    #pragma unroll
    for (int k = 0; k < DI2; k++) a += xv[k]*wr[k];
    dbl_s[wave][lane] = a;
    if (valid) {
      if (lane >= 2 && lane < 18)      BSb[(size_t)tok*DST + (lane-2)]  = a;
      else if (lane >= 18)             CSb[(size_t)tok*DST + (lane-18)] = a;
    }
  }
  __syncthreads();
  if (lane < DI2 && valid) {
    int d = lane;
    float raw = dbl_s[wave][0]*dtw[d*2] + dbl_s[wave][1]*dtw[d*2+1] + dtb[d];
    DT[(size_t)tok*DI2 + d] = softplusf_(raw);
  }
}

// -------- K3: chunk-parallel selective scan --------
template<int DI, int LT, int CL>
__global__ void scan1(const float* __restrict__ XS, const float* __restrict__ DT,
                      const float* __restrict__ BSb, const float* __restrict__ Alog,
                      float* __restrict__ PRD, float* __restrict__ ACC) {
  int sc = blockIdx.x / NCHUNK, c = blockIdx.x % NCHUNK;
  int d = threadIdx.x;
  float A[DST], P[DST], S[DST];
  const float4* Ap = (const float4*)(Alog + d*DST);
  #pragma unroll
  for (int q = 0; q < 4; q++) {
    float4 av = Ap[q];
    A[q*4+0] = -__expf(av.x); A[q*4+1] = -__expf(av.y);
    A[q*4+2] = -__expf(av.z); A[q*4+3] = -__expf(av.w);
  }
  #pragma unroll
  for (int i = 0; i < DST; i++) { P[i] = 1.f; S[i] = 0.f; }
  int t0 = c*CL, t1 = t0 + CL; if (t1 > LT) t1 = LT;
  size_t base = (size_t)sc * LT;
  for (int t = t0; t < t1; t++) {
    size_t tb = base + t;
    float dtv = DT[tb*DI + d];
    float xsv = XS[tb*DI + d];
    float du = dtv * xsv;
    const float4* Bp = (const float4*)(BSb + tb*DST);
    float Bv[DST];
    ((float4*)Bv)[0]=Bp[0]; ((float4*)Bv)[1]=Bp[1]; ((float4*)Bv)[2]=Bp[2]; ((float4*)Bv)[3]=Bp[3];
    #pragma unroll
    for (int i = 0; i < DST; i++) {
      float a = __expf(dtv*A[i]);
      P[i] *= a;
      S[i] = S[i]*a + du*Bv[i];
    }
  }
  float* pp = PRD + (((size_t)sc*NCHUNK + c)*DI + d)*DST;
  float* sp = ACC + (((size_t)sc*NCHUNK + c)*DI + d)*DST;
  #pragma unroll
  for (int q = 0; q < 4; q++) {
    ((float4*)pp)[q] = ((float4*)P)[q];
    ((float4*)sp)[q] = ((float4*)S)[q];
  }
}

template<int DI>
__global__ __launch_bounds__(256) void scan2(const float* __restrict__ PRD, float* __restrict__ ACC, int nthread) {
  int tid = blockIdx.x*256 + threadIdx.x;
  if (tid >= nthread) return;
  int sc = tid / (DI*DST);
  int rem = tid % (DI*DST);
  float h = 0.f;
  size_t idx = (size_t)sc*NCHUNK*DI*DST + rem;
  #pragma unroll 4
  for (int c = 0; c < NCHUNK; c++) {
    float p = PRD[idx];
    float s = ACC[idx];
    ACC[idx] = h;
    h = p*h + s;
    idx += (size_t)DI*DST;
  }
}

template<int DI, int LT, int CL>
__global__ void scan3(const float* __restrict__ XS, float* __restrict__ DT,
                      const float* __restrict__ BSb, const float* __restrict__ CSb,
                      const float* __restrict__ XZ, const float* __restrict__ Alog,
                      const float* __restrict__ Dp, const float* __restrict__ ACC) {
  int sc = blockIdx.x / NCHUNK, c = blockIdx.x % NCHUNK;
  int d = threadIdx.x;
  float A[DST], h[DST];
  const float4* Ap = (const float4*)(Alog + d*DST);
  #pragma unroll
  for (int q = 0; q < 4; q++) {
    float4 av = Ap[q];
    A[q*4+0] = -__expf(av.x); A[q*4+1] = -__expf(av.y);
    A[q*4+2] = -__expf(av.z); A[q*4+3] = -__expf(av.w);
  }
  const float4* hp = (const float4*)(ACC + (((size_t)sc*NCHUNK + c)*DI + d)*DST);
  float h4[4];
  #pragma unroll
  for (int q = 0; q < 4; q++) ((float4*)h)[q] = hp[q];
  (void)h4;
  float Dd = Dp[d];
  int t0 = c*CL, t1 = t0 + CL; if (t1 > LT) t1 = LT;
  size_t base = (size_t)sc * LT;
  for (int t = t0; t < t1; t++) {
    size_t tb = base + t;
    float dtv = DT[tb*DI + d];
    float xsv = XS[tb*DI + d];
    float du = dtv * xsv;
    const float4* Bp = (const float4*)(BSb + tb*DST);
    const float4* Cp = (const float4*)(CSb + tb*DST);
    float Bv[DST], Cv[DST];
    ((float4*)Bv)[0]=Bp[0]; ((float4*)Bv)[1]=Bp[1]; ((float4*)Bv)[2]=Bp[2]; ((float4*)Bv)[3]=Bp[3];
    ((float4*)Cv)[0]=Cp[0]; ((float4*)Cv)[1]=Cp[1]; ((float4*)Cv)[2]=Cp[2]; ((float4*)Cv)[3]=Cp[3];
    float y = 0.f;
    #pragma unroll
    for (int i = 0; i < DST; i++) {
      float a = __expf(dtv*A[i]);
      h[i] = h[i]*a + du*Bv[i];
      y += h[i]*Cv[i];
    }
    float z = XZ[tb*(2*DI) + DI + d];
    DT[tb*DI + d] = (y + xsv*Dd) * siluf_(z);
  }
}

// -------- proj: out_proj into token-major Y buffers (coalesced, no atomics) --------
// Y0[(n*L0 + s)*DM0 + dm], block = 8 tokens x 32 dm = 256 threads; L0 % 8 == 0
__global__ __launch_bounds__(256) void proj_b0(const float* __restrict__ G, const float* __restrict__ wo,
                                               float* __restrict__ Y0, int seq0) {
  __shared__ float wsm_t[DI0*DM0];   // [k][o]
  __shared__ float gsm[8*DI0];
  for (int i = threadIdx.x; i < DI0*DM0; i += 256) {
    int k = i >> 5, o = i & 31;
    wsm_t[i] = wo[o*DI0 + k];
  }
  int b = blockIdx.x;
  int nl = b / (L0/8), s0 = (b % (L0/8))*8;
  size_t gbase = ((size_t)nl*LT0 + s0 + 1)*DI0;
  gsm[threadIdx.x]       = G[gbase + threadIdx.x];
  gsm[threadIdx.x + 256] = G[gbase + threadIdx.x + 256];
  __syncthreads();
  int tl = threadIdx.x >> 5, dm = threadIdx.x & 31;
  const float* gv = gsm + tl*DI0;
  float acc = 0.f;
  #pragma unroll
  for (int k = 0; k < DI0; k++) acc += gv[k]*wsm_t[k*DM0 + dm];
  Y0[((size_t)(seq0 + nl)*L0 + s0)*DM0 + threadIdx.x] = acc;
}

// Y12[(gid*L12 + s)*DM2 + dm], block = 8 tokens x 24 dm = 192 threads; L12 % 8 == 0
__global__ __launch_bounds__(192) void proj_b12(const float* __restrict__ G, const float* __restrict__ wo,
                                                float* __restrict__ Y12, int seq0) {
  __shared__ float wsm_t[DI2*DM2];   // [k][o]
  __shared__ float gsm[8*DI2];
  for (int i = threadIdx.x; i < DI2*DM2; i += 192) {
    int k = i / DM2, o = i % DM2;
    wsm_t[i] = wo[o*DI2 + k];
  }
  int b = blockIdx.x;
  int nl = b / (L12/8), s0 = (b % (L12/8))*8;
  size_t gbase = ((size_t)nl*LT12 + s0 + 1)*DI2;
  gsm[threadIdx.x]       = G[gbase + threadIdx.x];
  gsm[threadIdx.x + 192] = G[gbase + threadIdx.x + 192];
  __syncthreads();
  int tl = threadIdx.x / DM2, dm = threadIdx.x % DM2;
  const float* gv = gsm + tl*DI2;
  float acc = 0.f;
  #pragma unroll
  for (int k = 0; k < DI2; k++) acc += gv[k]*wsm_t[k*DM2 + dm];
  Y12[((size_t)(seq0 + nl)*L12 + s0)*DM2 + threadIdx.x] = acc;
}

// -------- fold: gather all three contributions, coalesced out write --------
// out[c][h][w]; n=h/3, i=(h%3)*8+w/24, j=w%24
// m0 = Y0[(n*L0 + p*48+q)*32 + c/4], p=2i+((c>>1)&1), q=2j+(c&1)
// o1 = Y12[(n*L12 + c*24 + j)*24 + i]
// o2 = Y12[((64+n)*L12 + c*24 + i)*24 + j]
__global__ __launch_bounds__(256) void fold_out(const float* __restrict__ Y0, const float* __restrict__ Y12,
                                                float* __restrict__ out) {
  int idx = blockIdx.x*256 + threadIdx.x;          // < 128*192*192
  int w = idx % W_;
  int h = (idx / W_) % H_;
  int c = idx / (W_*H_);
  int n = h / 3;
  int i = (h % 3)*8 + w/24;
  int j = w % 24;
  int p = 2*i + ((c>>1)&1);
  int q = 2*j + (c&1);
  float m0 = Y0[((size_t)n*L0 + p*48 + q)*DM0 + (c>>2)];
  float o1 = Y12[((size_t)n*L12 + c*24 + j)*DM2 + i];
  float o2 = Y12[((size_t)(64+n)*L12 + c*24 + i)*DM2 + j];
  out[idx] = (m0 + o1 + o2) * (1.f/3.f);
}

extern "C" void kernel_launch(void* const* d_in, const int* in_sizes, int n_in,
                              void* d_out, int out_size, void* d_ws, size_t ws_size,
                              hipStream_t stream) {
  const float* x       = (const float*)d_in[0];
  const float* norm_w  = (const float*)d_in[1];
  const float* norm_b  = (const float*)d_in[2];
  const float* norm2_w = (const float*)d_in[3];
  const float* norm2_b = (const float*)d_in[4];
  const float* gt1     = (const float*)d_in[5];
  const float* gt2     = (const float*)d_in[6];
  const float* m1_inw  = (const float*)d_in[7];
  const float* m1_cw   = (const float*)d_in[8];
  const float* m1_cb   = (const float*)d_in[9];
  const float* m1_xpw  = (const float*)d_in[10];
  const float* m1_dtw  = (const float*)d_in[11];
  const float* m1_dtb  = (const float*)d_in[12];
  const float* m1_alog = (const float*)d_in[13];
  const float* m1_D    = (const float*)d_in[14];
  const float* m1_ow   = (const float*)d_in[15];
  const float* m2_inw  = (const float*)d_in[16];
  const float* m2_cw   = (const float*)d_in[17];
  const float* m2_cb   = (const float*)d_in[18];
  const float* m2_xpw  = (const float*)d_in[19];
  const float* m2_dtw  = (const float*)d_in[20];
  const float* m2_dtb  = (const float*)d_in[21];
  const float* m2_alog = (const float*)d_in[22];
  const float* m2_D    = (const float*)d_in[23];
  const float* m2_ow   = (const float*)d_in[24];
  float* out = (float*)d_out;

  size_t wsf = ws_size / sizeof(float);

  // persistent projection buffers
  const size_t nY0  = (size_t)NS0*L0*DM0;    // 4,718,592
  const size_t nY12 = (size_t)NS12*L12*DM2;  // 9,437,184
  float* Y0  = (float*)d_ws;
  float* Y12 = Y0 + nY0;
  float* SCR = Y12 + nY12;
  size_t scrf = wsf - (nY0 + nY12);

  // ---- branch 0 (m1), chunked over sequences to fit scratch ----
  {
    const size_t perState = (size_t)NCHUNK*DI0*DST;
    const size_t per = (size_t)LT0*(2*DI0 + DI0 + DI0 + 2*DST) + 2*perState; // 729,376 floats/seq
    int cap = (int)(scrf / per); if (cap < 1) cap = 1; if (cap > NS0) cap = NS0;
    float* XZ  = SCR;
    float* XS  = XZ + (size_t)cap*LT0*(2*DI0);
    float* DT  = XS + (size_t)cap*LT0*DI0;
    float* BSb = DT + (size_t)cap*LT0*DI0;
    float* CSb = BSb + (size_t)cap*LT0*DST;
    float* PRD = CSb + (size_t)cap*LT0*DST;
    float* ACC = PRD + (size_t)cap*perState;
    for (int s0 = 0; s0 < NS0; s0 += cap) {
      int cs = (NS0 - s0 < cap) ? (NS0 - s0) : cap;
      int ntok = cs * LT0;
      k1_b0<<<(ntok+3)/4, 256, 0, stream>>>(x, gt1, norm_w, norm_b, m1_inw, XZ, s0, ntok);
      k2_b0<<<(ntok+3)/4, 256, 0, stream>>>(XZ, m1_cw, m1_cb, m1_xpw, m1_dtw, m1_dtb, XS, DT, BSb, CSb, ntok);
      scan1<DI0, LT0, CL0><<<cs*NCHUNK, DI0, 0, stream>>>(XS, DT, BSb, m1_alog, PRD, ACC);
      scan2<DI0><<<(cs*DI0*DST+255)/256, 256, 0, stream>>>(PRD, ACC, cs*DI0*DST);
      scan3<DI0, LT0, CL0><<<cs*NCHUNK, DI0, 0, stream>>>(XS, DT, BSb, CSb, XZ, m1_alog, m1_D, ACC);
      proj_b0<<<cs*(L0/8), 256, 0, stream>>>(DT, m1_ow, Y0, s0);
    }
  }

  // ---- branches 1+2 (m2 shared weights; global seq id 0..127, branch = id>>6) ----
  {
    const size_t perState = (size_t)NCHUNK*DI2*DST;
    const size_t per = (size_t)LT12*(2*DI2 + DI2 + DI2 + 2*DST) + 2*perState; // 737,504 floats/seq
    int cap = (int)(scrf / per); if (cap < 1) cap = 1; if (cap > NS12) cap = NS12;
    float* XZ  = SCR;
    float* XS  = XZ + (size_t)cap*LT12*(2*DI2);
    float* DT  = XS + (size_t)cap*LT12*DI2;
    float* BSb = DT + (size_t)cap*LT12*DI2;
    float* CSb = BSb + (size_t)cap*LT12*DST;
    float* PRD = CSb + (size_t)cap*LT12*DST;
    float* ACC = PRD + (size_t)cap*perState;
    for (int s0 = 0; s0 < NS12; s0 += cap) {
      int cs = (NS12 - s0 < cap) ? (NS12 - s0) : cap;
      int ntok = cs * LT12;
      k1_b12<<<(ntok+3)/4, 256, 0, stream>>>(x, gt2, norm2_w, norm2_b, m2_inw, XZ, s0, ntok);
      k2_b12<<<(ntok+3)/4, 256, 0, stream>>>(XZ, m2_cw, m2_cb, m2_xpw, m2_dtw, m2_dtb, XS, DT, BSb, CSb, ntok);
      scan1<DI2, LT12, CL12><<<cs*NCHUNK, DI2, 0, stream>>>(XS, DT, BSb, m2_alog, PRD, ACC);
      scan2<DI2><<<(cs*DI2*DST+255)/256, 256, 0, stream>>>(PRD, ACC, cs*DI2*DST);
      scan3<DI2, LT12, CL12><<<cs*NCHUNK, DI2, 0, stream>>>(XS, DT, BSb, CSb, XZ, m2_alog, m2_D, ACC);
      proj_b12<<<cs*(L12/8), 192, 0, stream>>>(DT, m2_ow, Y12, s0);
    }
  }

  // ---- final fold: average of the three folded branch outputs ----
  fold_out<<<(C_*H_*W_)/256, 256, 0, stream>>>(Y0, Y12, out);
}

// Round 5
// 1300.298 us; speedup vs baseline: 4.9415x; 1.2460x over previous
//
#include <hip/hip_runtime.h>
#include <math.h>

// Problem dims
#define H_   192
#define W_   192
#define C_   128
#define CS_  24

// branch 0 (m1)
#define DM0  32
#define DI0  64
#define L0   2304
#define LT0  2305
#define NS0  64

// branches 1+2 (m2, shared weights) run as 128 sequences
#define DM2  24
#define DI2  48
#define L12  3072
#define LT12 3073
#define NS12 128

#define DST  16
#define NCHUNK 32
#define CL0  ((LT0 + NCHUNK - 1) / NCHUNK)    // 73
#define CL12 ((LT12 + NCHUNK - 1) / NCHUNK)   // 97

__device__ __forceinline__ float sigmoidf_(float x){ return 1.f/(1.f+__expf(-x)); }
__device__ __forceinline__ float siluf_(float x){ return x*sigmoidf_(x); }
__device__ __forceinline__ float softplusf_(float x){ return (x > 20.f) ? x : log1pf(__expf(x)); }

// ======== front: gather+LN+in_proj+conv+silu+x_proj+dt+scan1-compose ========
// one block (256 thr) per (local seq, chunk)
template<int DM, int DI, int LT, int CL, int BID>
__global__ __launch_bounds__(256) void front(
    const float* __restrict__ x, const float* __restrict__ gt,
    const float* __restrict__ nw, const float* __restrict__ nb,
    const float* __restrict__ win, const float* __restrict__ cw,
    const float* __restrict__ cb, const float* __restrict__ xpw,
    const float* __restrict__ dtw, const float* __restrict__ dtb,
    const float* __restrict__ Alog,
    float* __restrict__ XS, float* __restrict__ DT,
    float* __restrict__ Bb, float* __restrict__ Cb, float* __restrict__ GATE,
    float* __restrict__ PRD, float* __restrict__ ACC, int seq0)
{
  constexpr int NR = CL + 3;
  constexpr int R3A = 2*DI*DM;
  constexpr int R3B = CL*36 + 34*DI;
  constexpr int R3 = (R3A > R3B) ? R3A : R3B;
  constexpr int SMEMF = NR*DI + CL*DI + R3;
  __shared__ float smem[SMEMF];
  float* xsin = smem;                 // [NR][DI]; phase5+: dtl [CL][DI]
  float* dtl  = smem;
  float* xsc  = smem + NR*DI;         // [CL][DI]; phase1-2: xn [NR][DM] overlay
  float* xn   = xsc;
  float* r3   = smem + NR*DI + CL*DI;
  float* wint = r3;                   // [DM][2*DI] transposed in_proj weights
  float* dbl  = r3;                   // [CL][36] (phase4+)
  float* xpwt = r3 + CL*36;           // [DI][34] transposed x_proj weights

  const int tid = threadIdx.x;
  const int sc = blockIdx.x / NCHUNK, c = blockIdx.x % NCHUNK;
  const int gid = seq0 + sc;
  const int t0 = c*CL;
  int nt = LT - t0; if (nt > CL) nt = CL;

  // stage win transposed: wint[k*2DI + dd] = win[dd*DM + k]
  for (int i = tid; i < 2*DI*DM; i += 256) {
    int k = i / (2*DI), dd = i - k*(2*DI);
    wint[i] = win[dd*DM + k];
  }
  // phase 1: gather + LN -> xn (two tokens per wave via 32-lane halves)
  {
    int hw = tid >> 5, dm = tid & 31;
    for (int r = hw; r < nt + 3; r += 8) {
      int t = t0 - 3 + r;
      float v = 0.f;
      if (t >= 0 && dm < DM) {
        if (t == 0) v = gt[dm];
        else {
          int s = t - 1;
          if (BID == 0) {
            int p = s / 48, q = s - p*48;
            int cc = dm*4 + (p&1)*2 + (q&1);
            int ii = p >> 1, jj = q >> 1;
            v = x[cc*(H_*W_) + ((gid>>3)*CS_ + ii)*W_ + (gid&7)*CS_ + jj];
          } else {
            int cc = s / 24, rr = s - cc*24;
            int n = gid & 63, br = gid >> 6;
            int ii = br ? rr : dm;
            int jj = br ? dm : rr;
            v = x[cc*(H_*W_) + ((n>>3)*CS_ + ii)*W_ + (n&7)*CS_ + jj];
          }
        }
      }
      float s1 = (dm < DM) ? v : 0.f;
      float s2 = s1*s1;
      #pragma unroll
      for (int off = 1; off < 32; off <<= 1) {
        s1 += __shfl_xor(s1, off);
        s2 += __shfl_xor(s2, off);
      }
      if (t >= 0 && dm < DM) {
        float mean = s1 * (1.f/DM);
        float var = s2 * (1.f/DM) - mean*mean;
        xn[r*DM + dm] = (v - mean)*rsqrtf(var + 1e-5f)*nw[dm] + nb[dm];
      }
    }
  }
  __syncthreads();
  // phase 2: in_proj xs -> xsin ; z -> GATE = silu(z)
  for (int idx = tid; idx < (nt+3)*DI; idx += 256) {
    int r = idx / DI, d = idx - r*DI;
    int t = t0 - 3 + r;
    float acc = 0.f;
    if (t >= 0) {
      #pragma unroll
      for (int k = 0; k < DM; k++) acc += xn[r*DM + k]*wint[k*2*DI + d];
    }
    xsin[idx] = acc;
  }
  for (int idx = tid; idx < nt*DI; idx += 256) {
    int lt = idx / DI, d = idx - lt*DI;
    int r = lt + 3;
    float acc = 0.f;
    #pragma unroll
    for (int k = 0; k < DM; k++) acc += xn[r*DM + k]*wint[k*2*DI + DI + d];
    GATE[((size_t)sc*LT + t0 + lt)*DI + d] = siluf_(acc);
  }
  __syncthreads();
  // phase 3: conv+silu -> xsc + XS ; stage xpw transposed
  for (int idx = tid; idx < nt*DI; idx += 256) {
    int lt = idx / DI, d = idx - lt*DI;
    float acc = cb[d];
    #pragma unroll
    for (int k = 0; k < 4; k++) acc += cw[d*4 + k]*xsin[(lt + k)*DI + d];
    float v = siluf_(acc);
    xsc[idx] = v;
    XS[((size_t)sc*LT + t0 + lt)*DI + d] = v;
  }
  for (int i = tid; i < 34*DI; i += 256) {
    int d = i / 34, o = i - d*34;
    xpwt[i] = xpw[o*DI + d];
  }
  __syncthreads();
  // phase 4: x_proj -> dbl ; write B/C
  for (int idx = tid; idx < nt*34; idx += 256) {
    int lt = idx / 34, o = idx - lt*34;
    float acc = 0.f;
    #pragma unroll
    for (int d = 0; d < DI; d++) acc += xsc[lt*DI + d]*xpwt[d*34 + o];
    dbl[lt*36 + o] = acc;
    if (o >= 2) {
      size_t tb = (size_t)sc*LT + t0 + lt;
      if (o < 18) Bb[tb*DST + (o-2)] = acc;
      else        Cb[tb*DST + (o-18)] = acc;
    }
  }
  __syncthreads();
  // phase 5: dt -> dtl (overwrites xsin) + DT
  for (int idx = tid; idx < nt*DI; idx += 256) {
    int lt = idx / DI, d = idx - lt*DI;
    float raw = dbl[lt*36]*dtw[2*d] + dbl[lt*36 + 1]*dtw[2*d + 1] + dtb[d];
    float v = softplusf_(raw);
    dtl[idx] = v;
    DT[((size_t)sc*LT + t0 + lt)*DI + d] = v;
  }
  __syncthreads();
  // phase 6: scan1 chunk composition (P = prod a, S = sum suffixprod*b)
  for (int p = tid; p < DI*DST; p += 256) {
    int d = p >> 4, i = p & 15;
    float Ad = -__expf(Alog[p]);
    float P = 1.f, S = 0.f;
    for (int lt = 0; lt < nt; lt++) {
      float dtv = dtl[lt*DI + d];
      float du = dtv * xsc[lt*DI + d];
      float Bv = dbl[lt*36 + 2 + i];
      float a = __expf(dtv*Ad);
      P *= a;
      S = S*a + du*Bv;
    }
    size_t ob = (size_t)(sc*NCHUNK + c)*DI*DST + p;
    PRD[ob] = P;
    ACC[ob] = S;
  }
}

// ======== scan2: chunk-level scan; leaves per-chunk h_init in ACC ========
template<int DI>
__global__ __launch_bounds__(256) void scan2(const float* __restrict__ PRD, float* __restrict__ ACC, int nthread) {
  int tid = blockIdx.x*256 + threadIdx.x;
  if (tid >= nthread) return;
  int sc = tid / (DI*DST);
  int rem = tid - sc*(DI*DST);
  float h = 0.f;
  size_t idx = (size_t)sc*NCHUNK*DI*DST + rem;
  #pragma unroll 4
  for (int c = 0; c < NCHUNK; c++) {
    float p = PRD[idx];
    float s = ACC[idx];
    ACC[idx] = h;
    h = p*h + s;
    idx += (size_t)DI*DST;
  }
}

// ======== scan3p: scan from h_init + skip + gate + fused out_proj -> Y ========
// one block (DI threads, single wave) per (local seq, chunk)
template<int DM, int DI, int LT, int CL, int LSEQ>
__global__ __launch_bounds__(64) void scan3p(
    const float* __restrict__ XS, const float* __restrict__ DT,
    const float* __restrict__ Bb, const float* __restrict__ Cb,
    const float* __restrict__ GATE, const float* __restrict__ Alog,
    const float* __restrict__ Dp, const float* __restrict__ ACC,
    const float* __restrict__ wo, float* __restrict__ Y, int seq0)
{
  __shared__ float wot[DI*DM];   // [k][dm] transposed out_proj weights
  __shared__ float gl[DI];
  int d = threadIdx.x;
  for (int i = d; i < DI*DM; i += DI) {
    int k = i / DM, o = i - k*DM;
    wot[i] = wo[o*DI + k];
  }
  int sc = blockIdx.x / NCHUNK, c = blockIdx.x % NCHUNK;
  float A[DST], h[DST];
  const float4* Ap = (const float4*)(Alog + d*DST);
  #pragma unroll
  for (int q = 0; q < 4; q++) {
    float4 av = Ap[q];
    A[q*4+0] = -__expf(av.x); A[q*4+1] = -__expf(av.y);
    A[q*4+2] = -__expf(av.z); A[q*4+3] = -__expf(av.w);
  }
  const float4* hp = (const float4*)(ACC + ((size_t)(sc*NCHUNK + c)*DI + d)*DST);
  #pragma unroll
  for (int q = 0; q < 4; q++) ((float4*)h)[q] = hp[q];
  float Dd = Dp[d];
  int t0 = c*CL, t1 = t0 + CL; if (t1 > LT) t1 = LT;
  size_t base = (size_t)sc*LT;
  size_t ybase = (size_t)(seq0 + sc)*LSEQ;
  __syncthreads();
  for (int t = t0; t < t1; t++) {
    size_t tb = base + t;
    float dtv = DT[tb*DI + d];
    float xsv = XS[tb*DI + d];
    float du = dtv*xsv;
    float Bv[DST], Cv[DST];
    const float4* Bp = (const float4*)(Bb + tb*DST);
    const float4* Cp = (const float4*)(Cb + tb*DST);
    ((float4*)Bv)[0]=Bp[0]; ((float4*)Bv)[1]=Bp[1]; ((float4*)Bv)[2]=Bp[2]; ((float4*)Bv)[3]=Bp[3];
    ((float4*)Cv)[0]=Cp[0]; ((float4*)Cv)[1]=Cp[1]; ((float4*)Cv)[2]=Cp[2]; ((float4*)Cv)[3]=Cp[3];
    float y = 0.f;
    #pragma unroll
    for (int i = 0; i < DST; i++) {
      float a = __expf(dtv*A[i]);
      h[i] = h[i]*a + du*Bv[i];
      y += h[i]*Cv[i];
    }
    float g = (y + xsv*Dd) * GATE[tb*DI + d];
    __syncthreads();
    gl[d] = g;
    __syncthreads();
    if (d < DM && t > 0) {
      float acc = 0.f;
      #pragma unroll
      for (int k = 0; k < DI; k++) acc += gl[k]*wot[k*DM + d];
      Y[(ybase + (t-1))*DM + d] = acc;
    }
  }
}

// ======== fold: gather all three contributions, coalesced out write ========
// out[c][h][w]; n=h/3, i=(h%3)*8+w/24, j=w%24
__global__ __launch_bounds__(256) void fold_out(const float* __restrict__ Y0, const float* __restrict__ Y12,
                                                float* __restrict__ out) {
  int idx = blockIdx.x*256 + threadIdx.x;          // < 128*192*192
  int w = idx % W_;
  int h = (idx / W_) % H_;
  int c = idx / (W_*H_);
  int n = h / 3;
  int i = (h % 3)*8 + w/24;
  int j = w % 24;
  int p = 2*i + ((c>>1)&1);
  int q = 2*j + (c&1);
  float m0 = Y0[((size_t)n*L0 + p*48 + q)*DM0 + (c>>2)];
  float o1 = Y12[((size_t)n*L12 + c*24 + j)*DM2 + i];
  float o2 = Y12[((size_t)(64+n)*L12 + c*24 + i)*DM2 + j];
  out[idx] = (m0 + o1 + o2) * (1.f/3.f);
}

extern "C" void kernel_launch(void* const* d_in, const int* in_sizes, int n_in,
                              void* d_out, int out_size, void* d_ws, size_t ws_size,
                              hipStream_t stream) {
  const float* x       = (const float*)d_in[0];
  const float* norm_w  = (const float*)d_in[1];
  const float* norm_b  = (const float*)d_in[2];
  const float* norm2_w = (const float*)d_in[3];
  const float* norm2_b = (const float*)d_in[4];
  const float* gt1     = (const float*)d_in[5];
  const float* gt2     = (const float*)d_in[6];
  const float* m1_inw  = (const float*)d_in[7];
  const float* m1_cw   = (const float*)d_in[8];
  const float* m1_cb   = (const float*)d_in[9];
  const float* m1_xpw  = (const float*)d_in[10];
  const float* m1_dtw  = (const float*)d_in[11];
  const float* m1_dtb  = (const float*)d_in[12];
  const float* m1_alog = (const float*)d_in[13];
  const float* m1_D    = (const float*)d_in[14];
  const float* m1_ow   = (const float*)d_in[15];
  const float* m2_inw  = (const float*)d_in[16];
  const float* m2_cw   = (const float*)d_in[17];
  const float* m2_cb   = (const float*)d_in[18];
  const float* m2_xpw  = (const float*)d_in[19];
  const float* m2_dtw  = (const float*)d_in[20];
  const float* m2_dtb  = (const float*)d_in[21];
  const float* m2_alog = (const float*)d_in[22];
  const float* m2_D    = (const float*)d_in[23];
  const float* m2_ow   = (const float*)d_in[24];
  float* out = (float*)d_out;

  size_t wsf = ws_size / sizeof(float);

  // persistent projection buffers
  const size_t nY0  = (size_t)NS0*L0*DM0;    // 4,718,592
  const size_t nY12 = (size_t)NS12*L12*DM2;  // 9,437,184
  float* Y0  = (float*)d_ws;
  float* Y12 = Y0 + nY0;
  float* SCR = Y12 + nY12;
  size_t scrf = wsf - (nY0 + nY12);

  // ---- branch 0 (m1) ----
  {
    const size_t perState = (size_t)NCHUNK*DI0*DST;                       // 32768
    const size_t per = (size_t)LT0*(3*DI0 + 2*DST) + 2*perState;          // 581,856 floats/seq
    int cap = (int)(scrf / per); if (cap < 1) cap = 1; if (cap > NS0) cap = NS0;
    float* XS  = SCR;
    float* DT  = XS + (size_t)cap*LT0*DI0;
    float* Bb  = DT + (size_t)cap*LT0*DI0;
    float* Cb  = Bb + (size_t)cap*LT0*DST;
    float* GT  = Cb + (size_t)cap*LT0*DST;
    float* PRD = GT + (size_t)cap*LT0*DI0;
    float* ACC = PRD + (size_t)cap*perState;
    for (int s0 = 0; s0 < NS0; s0 += cap) {
      int cs = (NS0 - s0 < cap) ? (NS0 - s0) : cap;
      front<DM0, DI0, LT0, CL0, 0><<<cs*NCHUNK, 256, 0, stream>>>(
          x, gt1, norm_w, norm_b, m1_inw, m1_cw, m1_cb, m1_xpw, m1_dtw, m1_dtb,
          m1_alog, XS, DT, Bb, Cb, GT, PRD, ACC, s0);
      scan2<DI0><<<(cs*DI0*DST + 255)/256, 256, 0, stream>>>(PRD, ACC, cs*DI0*DST);
      scan3p<DM0, DI0, LT0, CL0, L0><<<cs*NCHUNK, DI0, 0, stream>>>(
          XS, DT, Bb, Cb, GT, m1_alog, m1_D, ACC, m1_ow, Y0, s0);
    }
  }

  // ---- branches 1+2 (m2 shared weights; global seq id 0..127, branch = id>>6) ----
  {
    const size_t perState = (size_t)NCHUNK*DI2*DST;                       // 24576
    const size_t per = (size_t)LT12*(3*DI2 + 2*DST) + 2*perState;         // 590,000 floats/seq
    int cap = (int)(scrf / per); if (cap < 1) cap = 1; if (cap > NS12) cap = NS12;
    float* XS  = SCR;
    float* DT  = XS + (size_t)cap*LT12*DI2;
    float* Bb  = DT + (size_t)cap*LT12*DI2;
    float* Cb  = Bb + (size_t)cap*LT12*DST;
    float* GT  = Cb + (size_t)cap*LT12*DST;
    float* PRD = GT + (size_t)cap*LT12*DI2;
    float* ACC = PRD + (size_t)cap*perState;
    for (int s0 = 0; s0 < NS12; s0 += cap) {
      int cs = (NS12 - s0 < cap) ? (NS12 - s0) : cap;
      front<DM2, DI2, LT12, CL12, 1><<<cs*NCHUNK, 256, 0, stream>>>(
          x, gt2, norm2_w, norm2_b, m2_inw, m2_cw, m2_cb, m2_xpw, m2_dtw, m2_dtb,
          m2_alog, XS, DT, Bb, Cb, GT, PRD, ACC, s0);
      scan2<DI2><<<(cs*DI2*DST + 255)/256, 256, 0, stream>>>(PRD, ACC, cs*DI2*DST);
      scan3p<DM2, DI2, LT12, CL12, L12><<<cs*NCHUNK, DI2, 0, stream>>>(
          XS, DT, Bb, Cb, GT, m2_alog, m2_D, ACC, m2_ow, Y12, s0);
    }
  }

  // ---- final fold ----
  fold_out<<<(C_*H_*W_)/256, 256, 0, stream>>>(Y0, Y12, out);
}